// Round 3
// baseline (152.687 us; speedup 1.0000x reference)
//
#include <hip/hip_runtime.h>
#include <hip/hip_bf16.h>

// Problem constants (match reference)
#define B_   8
#define NQ_  64     // N_CANDS
#define CTX_ 512    // CTX_LEN
#define DC_  512    // CONTEXT_SIZE
#define DQ_  512    // QUERY_SIZE
#define H_   256    // HIDDEN
#define EPS_ 1e-5f

using short8  = __attribute__((ext_vector_type(8))) short;  // 8 bf16 (4 VGPRs)
using floatx4 = __attribute__((ext_vector_type(4))) float;  // MFMA acc

// fp32 -> bf16 (RNE), bit-level
__device__ __forceinline__ short f2bf(float f) {
    union { float f; unsigned u; } c; c.f = f;
    unsigned r = (c.u + 0x7fffu + ((c.u >> 16) & 1u)) >> 16;
    return (short)r;
}

// ---------------------------------------------------------------------------
// Kernel 1: both input GEMMs via bf16 MFMA, no LDS.
// out2[r][h] = 2*(sum_k A[r][k]*W[h][k] + bias[h])   (pre-doubled for scoring)
// Block: 256 thr = 4 waves; tile 64M x 64N; wave w owns rows w*16..w*16+15.
// Fragment: lane holds A[m=lane&15][k = (lane>>4)*8 + j], K-contiguous 32B fp32
// -> cvt bf16 inline. 2-deep register pipeline over 16 K-steps (BK=32).
// ---------------------------------------------------------------------------
__global__ __launch_bounds__(256) void gemm_both_mfma(
    const float* __restrict__ ctx, const float* __restrict__ query,
    const float* __restrict__ W_c, const float* __restrict__ b_c,
    const float* __restrict__ W_q,
    float* __restrict__ res_c2, float* __restrict__ res_q2)
{
    const int rt = blockIdx.x;     // 0..71 row tiles (64 ctx + 8 query)
    const int ct = blockIdx.y;     // 0..3  col tiles

    const float* A; const float* W; const float* bias; float* outp; int row0;
    if (rt < 64) { A = ctx;   W = W_c; bias = b_c;     outp = res_c2; row0 = rt * 64; }
    else         { A = query; W = W_q; bias = nullptr; outp = res_q2; row0 = (rt - 64) * 64; }

    const int col0 = ct * 64;
    const int wave = threadIdx.x >> 6;
    const int lane = threadIdx.x & 63;
    const int m  = lane & 15;      // row/col within 16-tile
    const int kq = lane >> 4;      // k-quad: base k offset = kq*8

    const float* arow = A + (size_t)(row0 + wave * 16 + m) * 512 + kq * 8;
    const float* wrow0 = W + (size_t)(col0 +  0 + m) * 512 + kq * 8;
    const float* wrow1 = W + (size_t)(col0 + 16 + m) * 512 + kq * 8;
    const float* wrow2 = W + (size_t)(col0 + 32 + m) * 512 + kq * 8;
    const float* wrow3 = W + (size_t)(col0 + 48 + m) * 512 + kq * 8;

    floatx4 acc[4] = {};

    // pipeline buffers (fp32 raw), 2-deep
    float4 ra0[2], ra1[2];
    float4 rb0[2][4], rb1[2][4];

    auto load_step = [&](int k, int buf) {
        ra0[buf] = *(const float4*)(arow + k);
        ra1[buf] = *(const float4*)(arow + k + 4);
        rb0[buf][0] = *(const float4*)(wrow0 + k); rb1[buf][0] = *(const float4*)(wrow0 + k + 4);
        rb0[buf][1] = *(const float4*)(wrow1 + k); rb1[buf][1] = *(const float4*)(wrow1 + k + 4);
        rb0[buf][2] = *(const float4*)(wrow2 + k); rb1[buf][2] = *(const float4*)(wrow2 + k + 4);
        rb0[buf][3] = *(const float4*)(wrow3 + k); rb1[buf][3] = *(const float4*)(wrow3 + k + 4);
    };

    load_step(0, 0);
    #pragma unroll
    for (int s = 0; s < 16; ++s) {
        const int cur = s & 1, nx = cur ^ 1;
        if (s < 15) load_step((s + 1) * 32, nx);
        short8 af;
        af[0] = f2bf(ra0[cur].x); af[1] = f2bf(ra0[cur].y);
        af[2] = f2bf(ra0[cur].z); af[3] = f2bf(ra0[cur].w);
        af[4] = f2bf(ra1[cur].x); af[5] = f2bf(ra1[cur].y);
        af[6] = f2bf(ra1[cur].z); af[7] = f2bf(ra1[cur].w);
        #pragma unroll
        for (int j = 0; j < 4; ++j) {
            short8 bf;
            bf[0] = f2bf(rb0[cur][j].x); bf[1] = f2bf(rb0[cur][j].y);
            bf[2] = f2bf(rb0[cur][j].z); bf[3] = f2bf(rb0[cur][j].w);
            bf[4] = f2bf(rb1[cur][j].x); bf[5] = f2bf(rb1[cur][j].y);
            bf[6] = f2bf(rb1[cur][j].z); bf[7] = f2bf(rb1[cur][j].w);
            acc[j] = __builtin_amdgcn_mfma_f32_16x16x32_bf16(af, bf, acc[j], 0, 0, 0);
        }
    }

    // Epilogue: D[row=(lane>>4)*4+i][col=lane&15]; write 2*(acc+bias)
    #pragma unroll
    for (int j = 0; j < 4; ++j) {
        const int col = col0 + j * 16 + m;
        const float bb = bias ? bias[col] : 0.f;
        #pragma unroll
        for (int i = 0; i < 4; ++i) {
            const int row = row0 + wave * 16 + kq * 4 + i;
            outp[(size_t)row * H_ + col] = 2.f * (acc[j][i] + bb);
        }
    }
}

// ---------------------------------------------------------------------------
// Kernel 2: one 512-thread block per (b, q-pair). 256 blocks, XCD-swizzled.
//  logit = b_o + Sum(W_o) - 2*sum_h W_o[h]*rcp(exp(2x)+1)   [== W_o.tanh(x)]
//  with 2x = res_c2 + res_q2 (both pre-doubled by the GEMM).
// ---------------------------------------------------------------------------
__global__ __launch_bounds__(512) void attn_fused(
    const float* __restrict__ res_c2,  // B*CTX*H, pre-doubled
    const float* __restrict__ res_q2,  // B*NQ*H,  pre-doubled
    const float* __restrict__ context, // B*CTX*DC
    const float* __restrict__ mask,    // B*CTX
    const float* __restrict__ W_o,     // H
    const float* __restrict__ b_o_p,   // scalar
    float* __restrict__ out,           // B*NQ*DC
    float* __restrict__ wout)          // B*NQ*CTX
{
    __shared__ float rqs[2][H_];
    __shared__ float wos[H_];
    __shared__ float lg[2][CTX_];
    __shared__ float red[2][8];
    __shared__ float4 pc[2][128];

    const int b  = blockIdx.x & 7;     // XCD swizzle: batch b pinned to XCD b
    const int q0 = (blockIdx.x >> 3) * 2;
    const int tid  = threadIdx.x;
    const int wave = tid >> 6;
    const int lane = tid & 63;

    {
        const int qi = tid >> 8, h = tid & 255;
        rqs[qi][h] = res_q2[(size_t)(b * NQ_ + q0 + qi) * H_ + h];
        if (tid < H_) wos[tid] = W_o[tid];
    }
    __syncthreads();

    // Phase A: 16-lane groups own one c; lane bit 0-3 (cq) = h-chunk.
    const int cq = lane & 15;
    const int quad = lane >> 4;
    float4 rq0[4], rq1[4], wo[4];
    #pragma unroll
    for (int k = 0; k < 4; ++k) {
        rq0[k] = ((const float4*)rqs[0])[cq + 16 * k];
        rq1[k] = ((const float4*)rqs[1])[cq + 16 * k];
        wo[k]  = ((const float4*)wos)[cq + 16 * k];
    }
    // S = sum(W_o) via 16-lane butterfly (uniform in group)
    float S = wo[0].x + wo[0].y + wo[0].z + wo[0].w
            + wo[1].x + wo[1].y + wo[1].z + wo[1].w
            + wo[2].x + wo[2].y + wo[2].z + wo[2].w
            + wo[3].x + wo[3].y + wo[3].z + wo[3].w;
    S += __shfl_xor(S, 1); S += __shfl_xor(S, 2);
    S += __shfl_xor(S, 4); S += __shfl_xor(S, 8);
    const float base = *b_o_p + S;

    const float* rc_b = res_c2 + (size_t)b * CTX_ * H_;
    const int cbase = wave * 64;
    for (int it = 0; it < 16; ++it) {
        const int c = cbase + it * 4 + quad;
        const float* p = rc_b + (size_t)c * H_ + cq * 4;
        float4 x0 = *(const float4*)(p);
        float4 x1 = *(const float4*)(p + 64);
        float4 x2 = *(const float4*)(p + 128);
        float4 x3 = *(const float4*)(p + 192);
        float s0 = 0.f, s1 = 0.f;
        #define TERM(xc, rq0c, rq1c, wc)                                     \
            { float e0 = __expf((xc) + (rq0c));                              \
              s0 += (wc) * __builtin_amdgcn_rcpf(e0 + 1.f);                  \
              float e1 = __expf((xc) + (rq1c));                              \
              s1 += (wc) * __builtin_amdgcn_rcpf(e1 + 1.f); }
        TERM(x0.x, rq0[0].x, rq1[0].x, wo[0].x) TERM(x0.y, rq0[0].y, rq1[0].y, wo[0].y)
        TERM(x0.z, rq0[0].z, rq1[0].z, wo[0].z) TERM(x0.w, rq0[0].w, rq1[0].w, wo[0].w)
        TERM(x1.x, rq0[1].x, rq1[1].x, wo[1].x) TERM(x1.y, rq0[1].y, rq1[1].y, wo[1].y)
        TERM(x1.z, rq0[1].z, rq1[1].z, wo[1].z) TERM(x1.w, rq0[1].w, rq1[1].w, wo[1].w)
        TERM(x2.x, rq0[2].x, rq1[2].x, wo[2].x) TERM(x2.y, rq0[2].y, rq1[2].y, wo[2].y)
        TERM(x2.z, rq0[2].z, rq1[2].z, wo[2].z) TERM(x2.w, rq0[2].w, rq1[2].w, wo[2].w)
        TERM(x3.x, rq0[3].x, rq1[3].x, wo[3].x) TERM(x3.y, rq0[3].y, rq1[3].y, wo[3].y)
        TERM(x3.z, rq0[3].z, rq1[3].z, wo[3].z) TERM(x3.w, rq0[3].w, rq1[3].w, wo[3].w)
        #undef TERM
        s0 += __shfl_xor(s0, 1); s0 += __shfl_xor(s0, 2);
        s0 += __shfl_xor(s0, 4); s0 += __shfl_xor(s0, 8);
        s1 += __shfl_xor(s1, 1); s1 += __shfl_xor(s1, 2);
        s1 += __shfl_xor(s1, 4); s1 += __shfl_xor(s1, 8);
        if (cq == 0) { lg[0][c] = base - 2.f * s0; lg[1][c] = base - 2.f * s1; }
    }
    __syncthreads();

    // Phase B: softmax (reference-exact: no max-sub, denom = sum + EPS)
    const float mk = mask[b * CTX_ + tid];
    float e0 = mk * __expf(lg[0][tid]);
    float e1 = mk * __expf(lg[1][tid]);
    float l0 = e0, l1 = e1;
    #pragma unroll
    for (int off = 32; off; off >>= 1) {
        l0 += __shfl_down(l0, off);
        l1 += __shfl_down(l1, off);
    }
    if (lane == 0) { red[0][wave] = l0; red[1][wave] = l1; }
    __syncthreads();
    float d0 = EPS_, d1 = EPS_;
    #pragma unroll
    for (int w = 0; w < 8; ++w) { d0 += red[0][w]; d1 += red[1][w]; }
    const float w0 = e0 * (1.f / d0);
    const float w1 = e1 * (1.f / d1);
    lg[0][tid] = w0;
    lg[1][tid] = w1;
    wout[(size_t)(b * NQ_ + q0 + 0) * CTX_ + tid] = w0;
    wout[(size_t)(b * NQ_ + q0 + 1) * CTX_ + tid] = w1;
    __syncthreads();

    // Phase C: qi = tid>>8, ch = c-half, dt*4 = d. Combine halves via LDS.
    const int qi = tid >> 8;
    const int sub = tid & 255;
    const int ch = sub >> 7;
    const int dt = sub & 127;
    const float* cb = context + (size_t)b * CTX_ * DC_;
    float4 acc = make_float4(0.f, 0.f, 0.f, 0.f);
    const int c0 = ch * 256;
    #pragma unroll 4
    for (int c = c0; c < c0 + 256; ++c) {
        const float wv = lg[qi][c];
        float4 v = *(const float4*)&cb[(size_t)c * DC_ + dt * 4];
        acc.x += wv * v.x; acc.y += wv * v.y;
        acc.z += wv * v.z; acc.w += wv * v.w;
    }
    if (ch) pc[qi][dt] = acc;
    __syncthreads();
    if (!ch) {
        float4 p = pc[qi][dt];
        acc.x += p.x; acc.y += p.y; acc.z += p.z; acc.w += p.w;
        *(float4*)&out[(size_t)(b * NQ_ + q0 + qi) * DC_ + dt * 4] = acc;
    }
}

extern "C" void kernel_launch(void* const* d_in, const int* in_sizes, int n_in,
                              void* d_out, int out_size, void* d_ws, size_t ws_size,
                              hipStream_t stream) {
    const float* query   = (const float*)d_in[0];  // B,NQ,DQ
    const float* context = (const float*)d_in[1];  // B,CTX,DC
    const float* mask    = (const float*)d_in[2];  // B,CTX
    const float* W_c     = (const float*)d_in[3];  // H,DC
    const float* b_c     = (const float*)d_in[4];  // H
    const float* W_q     = (const float*)d_in[5];  // H,DQ
    const float* W_o     = (const float*)d_in[6];  // H
    const float* b_o     = (const float*)d_in[7];  // scalar

    float* out  = (float*)d_out;                   // B,NQ,DC
    float* wout = out + (size_t)B_ * NQ_ * DC_;    // B,NQ,CTX

    float* res_c2 = (float*)d_ws;                        // 4 MB (pre-doubled)
    float* res_q2 = res_c2 + (size_t)B_ * CTX_ * H_;     // 512 KB (pre-doubled)

    // both input GEMMs, bf16 MFMA: 72 row-tiles (64 ctx + 8 query) x 4 col-tiles
    gemm_both_mfma<<<dim3(72, 4), 256, 0, stream>>>(
        context, query, W_c, b_c, W_q, res_c2, res_q2);
    // fused scoring + softmax + weighted sum, 2 queries per block
    attn_fused<<<B_ * NQ_ / 2, 512, 0, stream>>>(
        res_c2, res_q2, context, mask, W_o, b_o, out, wout);
}

// Round 4
// 137.767 us; speedup vs baseline: 1.1083x; 1.1083x over previous
//
#include <hip/hip_runtime.h>
#include <hip/hip_bf16.h>

// Problem constants (match reference)
#define B_   8
#define NQ_  64     // N_CANDS
#define CTX_ 512    // CTX_LEN
#define DC_  512    // CONTEXT_SIZE
#define DQ_  512    // QUERY_SIZE
#define H_   256    // HIDDEN
#define EPS_ 1e-5f

using short8  = __attribute__((ext_vector_type(8))) short;  // 8 bf16 (4 VGPRs)
using floatx4 = __attribute__((ext_vector_type(4))) float;  // MFMA acc

// pack 2 fp32 -> bf16x2 (RNE), bit-level
__device__ __forceinline__ unsigned pk_bf16(float x, float y) {
    union { float f; unsigned u; } a, b;
    a.f = x; b.f = y;
    unsigned ra = (a.u + 0x7fffu + ((a.u >> 16) & 1u)) >> 16;
    unsigned rb = (b.u + 0x7fffu + ((b.u >> 16) & 1u)) & 0xffff0000u;
    return ra | rb;
}

// ---------------------------------------------------------------------------
// Kernel 1: both input GEMMs via bf16 MFMA with LDS-staged bf16 tiles.
// Epilogue writes Ec = exp(2*(acc+bias)) / Eq = exp(2*acc)  (factored-exp form:
// tanh(x) = 1 - 2/(e^{2x}+1), e^{2(rc+rq)} = Ec*Eq).
// Tile 64Mx64N, BK=32, 256 thr = 4 waves; wave w owns rows w*16..+15.
// ---------------------------------------------------------------------------
__global__ __launch_bounds__(256) void gemm_exp(
    const float* __restrict__ ctx, const float* __restrict__ query,
    const float* __restrict__ W_c, const float* __restrict__ b_c,
    const float* __restrict__ W_q,
    float* __restrict__ Ec, float* __restrict__ Eq)
{
    __shared__ unsigned short As[64][40];  // bf16, stride 40 (80B: 2-way banks only)
    __shared__ unsigned short Bs[64][40];

    const int rt = blockIdx.x;     // 0..71 (64 ctx + 8 query row-tiles)
    const int ct = blockIdx.y;     // 0..3

    const float* A; const float* W; const float* bias; float* outp; int row0;
    if (rt < 64) { A = ctx;   W = W_c; bias = b_c;     outp = Ec; row0 = rt * 64; }
    else         { A = query; W = W_q; bias = nullptr; outp = Eq; row0 = (rt - 64) * 64; }

    const int col0 = ct * 64;
    const int t    = threadIdx.x;
    const int wave = t >> 6;
    const int lane = t & 63;
    const int m  = lane & 15;
    const int kq = lane >> 4;

    const int r  = t >> 2;         // staging row 0..63
    const int sg = t & 3;          // staging 8-float k-segment
    const float* arow_g = A + (size_t)(row0 + r) * 512 + sg * 8;
    const float* brow_g = W + (size_t)(col0 + r) * 512 + sg * 8;

    floatx4 acc[4] = {};

    for (int k0 = 0; k0 < 512; k0 += 32) {
        float4 a0 = *(const float4*)(arow_g + k0);
        float4 a1 = *(const float4*)(arow_g + k0 + 4);
        float4 b0 = *(const float4*)(brow_g + k0);
        float4 b1 = *(const float4*)(brow_g + k0 + 4);
        __syncthreads();           // prior compute done before overwrite
        uint4 av, bv;
        av.x = pk_bf16(a0.x, a0.y); av.y = pk_bf16(a0.z, a0.w);
        av.z = pk_bf16(a1.x, a1.y); av.w = pk_bf16(a1.z, a1.w);
        bv.x = pk_bf16(b0.x, b0.y); bv.y = pk_bf16(b0.z, b0.w);
        bv.z = pk_bf16(b1.x, b1.y); bv.w = pk_bf16(b1.z, b1.w);
        *(uint4*)&As[r][sg * 8] = av;
        *(uint4*)&Bs[r][sg * 8] = bv;
        __syncthreads();

        short8 af = *(const short8*)&As[wave * 16 + m][kq * 8];
        #pragma unroll
        for (int j = 0; j < 4; ++j) {
            short8 bf = *(const short8*)&Bs[j * 16 + m][kq * 8];
            acc[j] = __builtin_amdgcn_mfma_f32_16x16x32_bf16(af, bf, acc[j], 0, 0, 0);
        }
    }

    // Epilogue: D[row=(lane>>4)*4+i][col=lane&15]; write exp(2*(acc+bias))
    #pragma unroll
    for (int j = 0; j < 4; ++j) {
        const int col = col0 + j * 16 + m;
        const float bb = bias ? bias[col] : 0.f;
        #pragma unroll
        for (int i = 0; i < 4; ++i) {
            const int row = row0 + wave * 16 + kq * 4 + i;
            outp[(size_t)row * H_ + col] = __expf(2.f * (acc[j][i] + bb));
        }
    }
}

// ---------------------------------------------------------------------------
// Kernel 2: scoring. Grid 512 = b(8) x ctile(8, 64c) x qgroup(8, 8q).
// Thread owns (c, q) pairs outright: NO cross-lane reduction.
//  logit = b_o + Sum(W_o) - 2*sum_h W_o[h]*rcp(Ec[c,h]*Eq[q,h] + 1)
// Writes e = mask * exp(logit) to eout.
// ---------------------------------------------------------------------------
__global__ __launch_bounds__(256) void score_kernel(
    const float* __restrict__ Ec,    // B*CTX*H
    const float* __restrict__ Eqm,   // B*NQ*H
    const float* __restrict__ W_o,   // H
    const float* __restrict__ b_o_p, // scalar
    const float* __restrict__ mask,  // B*CTX
    float* __restrict__ eout)        // B*NQ*CTX
{
    __shared__ float eqs[8 * H_];
    __shared__ float wos[H_];
    __shared__ float ecs[64][68];    // 64c x 64h chunk, padded
    __shared__ float redS[4];

    const int blk = blockIdx.x;
    const int b  = blk & 7;          // XCD swizzle
    const int ct = (blk >> 3) & 7;
    const int qg = blk >> 6;
    const int t  = threadIdx.x;

    const float* eq_base = Eqm + (size_t)(b * NQ_ + qg * 8) * H_;
    #pragma unroll
    for (int i = 0; i < 8; ++i) eqs[t + 256 * i] = eq_base[t + 256 * i];
    const float wo_own = W_o[t];
    wos[t] = wo_own;
    float S = wo_own;
    #pragma unroll
    for (int k = 1; k < 64; k <<= 1) S += __shfl_xor(S, k);
    if ((t & 63) == 0) redS[t >> 6] = S;
    __syncthreads();
    const float base = *b_o_p + redS[0] + redS[1] + redS[2] + redS[3];

    const int qi = t >> 5;           // 0..7
    const int cl = t & 31;           // 0..31 (owns c0+cl and c0+cl+32)
    const float* eqr = &eqs[qi * H_];
    const int c0 = ct * 64;
    const float* ec_tile = Ec + (size_t)(b * CTX_ + c0) * H_;

    const int sr = t >> 2, ssg = t & 3;   // staging: row, 16-float segment
    const float* ssrc = ec_tile + (size_t)sr * H_ + ssg * 16;

    float s0 = 0.f, s1 = 0.f;
    for (int hb = 0; hb < 4; ++hb) {
        {   // stage 64c x 64h fp32 chunk (coalesced float4 x4 per thread)
            const float* src = ssrc + hb * 64;
            float4 v0 = *(const float4*)(src);
            float4 v1 = *(const float4*)(src + 4);
            float4 v2 = *(const float4*)(src + 8);
            float4 v3 = *(const float4*)(src + 12);
            float* dst = &ecs[sr][ssg * 16];
            *(float4*)(dst)      = v0; *(float4*)(dst + 4)  = v1;
            *(float4*)(dst + 8)  = v2; *(float4*)(dst + 12) = v3;
        }
        __syncthreads();
        const float* eqh = eqr + hb * 64;
        const float* woh = wos + hb * 64;
        #pragma unroll
        for (int h4 = 0; h4 < 16; ++h4) {
            float4 eq4 = *(const float4*)(eqh + h4 * 4);   // broadcast
            float4 wo4 = *(const float4*)(woh + h4 * 4);   // broadcast
            float4 ea  = *(const float4*)&ecs[cl][h4 * 4];
            float4 eb  = *(const float4*)&ecs[cl + 32][h4 * 4];
            s0 += wo4.x * __builtin_amdgcn_rcpf(ea.x * eq4.x + 1.f);
            s0 += wo4.y * __builtin_amdgcn_rcpf(ea.y * eq4.y + 1.f);
            s0 += wo4.z * __builtin_amdgcn_rcpf(ea.z * eq4.z + 1.f);
            s0 += wo4.w * __builtin_amdgcn_rcpf(ea.w * eq4.w + 1.f);
            s1 += wo4.x * __builtin_amdgcn_rcpf(eb.x * eq4.x + 1.f);
            s1 += wo4.y * __builtin_amdgcn_rcpf(eb.y * eq4.y + 1.f);
            s1 += wo4.z * __builtin_amdgcn_rcpf(eb.z * eq4.z + 1.f);
            s1 += wo4.w * __builtin_amdgcn_rcpf(eb.w * eq4.w + 1.f);
        }
        __syncthreads();             // before next chunk overwrite
    }

    const int q = b * NQ_ + qg * 8 + qi;
    const int ca = c0 + cl, cb2 = c0 + cl + 32;
    eout[(size_t)q * CTX_ + ca]  = mask[b * CTX_ + ca]  * __expf(base - 2.f * s0);
    eout[(size_t)q * CTX_ + cb2] = mask[b * CTX_ + cb2] * __expf(base - 2.f * s1);
}

// ---------------------------------------------------------------------------
// Kernel 3: softmax (reference-exact: denom = sum + EPS) + weighted context sum.
// Grid 512 = b(8) x qgroup(8, 8q) x dslice(8, 64d). Softmax redundant per dslice.
// ---------------------------------------------------------------------------
__global__ __launch_bounds__(256) void out_kernel(
    const float* __restrict__ eout,    // B*NQ*CTX (mask*exp(logit))
    const float* __restrict__ context, // B*CTX*DC
    float* __restrict__ out,           // B*NQ*DC
    float* __restrict__ wout)          // B*NQ*CTX
{
    __shared__ float ws[8][CTX_];

    const int blk = blockIdx.x;
    const int b  = blk & 7;
    const int qg = (blk >> 3) & 7;
    const int dq = blk >> 6;           // 0..7: d in [dq*64, +64)
    const int t  = threadIdx.x;
    const int qi = t >> 5;
    const int cl = t & 31;

    const int q = b * NQ_ + qg * 8 + qi;
    const float* erow = eout + (size_t)q * CTX_;

    float ev[16];
    float part = 0.f;
    #pragma unroll
    for (int k = 0; k < 16; ++k) {
        ev[k] = erow[cl + 32 * k];
        part += ev[k];
    }
    // butterfly within the 32-lane q-group (xor<32 stays in half-wave)
    part += __shfl_xor(part, 1);  part += __shfl_xor(part, 2);
    part += __shfl_xor(part, 4);  part += __shfl_xor(part, 8);
    part += __shfl_xor(part, 16);
    const float inv = 1.f / (part + EPS_);
    #pragma unroll
    for (int k = 0; k < 16; ++k) {
        const float w = ev[k] * inv;
        ws[qi][cl + 32 * k] = w;
        if (dq == 0) wout[(size_t)q * CTX_ + cl + 32 * k] = w;
    }
    __syncthreads();

    // weighted sum: thread owns (q, d = dq*64 + cl*2) float2 over all 512 c
    const float* cb = context + (size_t)b * CTX_ * DC_ + dq * 64 + cl * 2;
    float ax = 0.f, ay = 0.f;
    #pragma unroll 8
    for (int c = 0; c < CTX_; ++c) {
        const float w = ws[qi][c];
        float2 v = *(const float2*)(cb + (size_t)c * DC_);
        ax += w * v.x; ay += w * v.y;
    }
    *(float2*)&out[(size_t)q * DC_ + dq * 64 + cl * 2] = make_float2(ax, ay);
}

extern "C" void kernel_launch(void* const* d_in, const int* in_sizes, int n_in,
                              void* d_out, int out_size, void* d_ws, size_t ws_size,
                              hipStream_t stream) {
    const float* query   = (const float*)d_in[0];  // B,NQ,DQ
    const float* context = (const float*)d_in[1];  // B,CTX,DC
    const float* mask    = (const float*)d_in[2];  // B,CTX
    const float* W_c     = (const float*)d_in[3];  // H,DC
    const float* b_c     = (const float*)d_in[4];  // H
    const float* W_q     = (const float*)d_in[5];  // H,DQ
    const float* W_o     = (const float*)d_in[6];  // H
    const float* b_o     = (const float*)d_in[7];  // scalar

    float* out  = (float*)d_out;                   // B,NQ,DC
    float* wout = out + (size_t)B_ * NQ_ * DC_;    // B,NQ,CTX

    float* Ec   = (float*)d_ws;                        // 4 MB: exp(2*res_c)
    float* Eq   = Ec + (size_t)B_ * CTX_ * H_;         // 512 KB: exp(2*res_q)
    float* eout = Eq + (size_t)B_ * NQ_ * H_;          // 1 MB: mask*exp(logit)

    gemm_exp<<<dim3(72, 4), 256, 0, stream>>>(
        context, query, W_c, b_c, W_q, Ec, Eq);
    score_kernel<<<512, 256, 0, stream>>>(
        Ec, Eq, W_o, b_o, mask, eout);
    out_kernel<<<512, 256, 0, stream>>>(
        eout, context, out, wout);
}

// Round 5
// 137.536 us; speedup vs baseline: 1.1102x; 1.0017x over previous
//
#include <hip/hip_runtime.h>
#include <hip/hip_bf16.h>

// Problem constants (match reference)
#define B_   8
#define NQ_  64     // N_CANDS
#define CTX_ 512    // CTX_LEN
#define DC_  512    // CONTEXT_SIZE
#define DQ_  512    // QUERY_SIZE
#define H_   256    // HIDDEN
#define EPS_ 1e-5f

using short8  = __attribute__((ext_vector_type(8))) short;  // 8 bf16 (4 VGPRs)
using floatx4 = __attribute__((ext_vector_type(4))) float;  // MFMA acc

// 2 fp32 -> packed bf16x2 via v_cvt_pk_bf16_f32 (single instruction on gfx950)
__device__ __forceinline__ unsigned pk2(float x, float y) {
    union { __hip_bfloat162 h; unsigned u; } c;
    c.h = __float22bfloat162_rn(make_float2(x, y));
    return c.u;
}
// 8 fp32 (two float4) -> short8 bf16 fragment
__device__ __forceinline__ short8 cvt8(float4 a, float4 b) {
    union { unsigned u[4]; short8 s; } r;
    r.u[0] = pk2(a.x, a.y); r.u[1] = pk2(a.z, a.w);
    r.u[2] = pk2(b.x, b.y); r.u[3] = pk2(b.z, b.w);
    return r.s;
}

// ---------------------------------------------------------------------------
// Kernel 1: both input GEMMs via bf16 MFMA; register-direct fragments, NO LDS,
// NO barriers. Epilogue: Ec = exp(2*(acc+bias)), Eq = exp(2*acc)
// (factored-exp form: tanh(x) = 1 - 2/(e^{2x}+1), e^{2(rc+rq)} = Ec*Eq).
// Tile 64Mx64N, 256 thr = 4 waves; wave w owns rows w*16..+15; all waves share
// the 64 W rows (L1-hot). Fragment: lane = A[m=lane&15][k=(lane>>4)*8+j].
// ---------------------------------------------------------------------------
__global__ __launch_bounds__(256) void gemm_exp(
    const float* __restrict__ ctx, const float* __restrict__ query,
    const float* __restrict__ W_c, const float* __restrict__ b_c,
    const float* __restrict__ W_q,
    float* __restrict__ Ec, float* __restrict__ Eq)
{
    const int rt = blockIdx.x;     // 0..71 (64 ctx + 8 query row-tiles)
    const int ct = blockIdx.y;     // 0..3

    const float* A; const float* W; const float* bias; float* outp; int row0;
    if (rt < 64) { A = ctx;   W = W_c; bias = b_c;     outp = Ec; row0 = rt * 64; }
    else         { A = query; W = W_q; bias = nullptr; outp = Eq; row0 = (rt - 64) * 64; }

    const int col0 = ct * 64;
    const int wave = threadIdx.x >> 6;
    const int lane = threadIdx.x & 63;
    const int m  = lane & 15;
    const int kq = lane >> 4;

    const float* arow = A + (size_t)(row0 + wave * 16 + m) * 512 + kq * 8;
    const float* w0 = W + (size_t)(col0 +  0 + m) * 512 + kq * 8;
    const float* w1 = W + (size_t)(col0 + 16 + m) * 512 + kq * 8;
    const float* w2 = W + (size_t)(col0 + 32 + m) * 512 + kq * 8;
    const float* w3 = W + (size_t)(col0 + 48 + m) * 512 + kq * 8;

    floatx4 acc[4] = {};

    #pragma unroll 2
    for (int s = 0; s < 16; ++s) {
        const int k = s * 32;
        short8 af = cvt8(*(const float4*)(arow + k), *(const float4*)(arow + k + 4));
        short8 b0 = cvt8(*(const float4*)(w0 + k), *(const float4*)(w0 + k + 4));
        short8 b1 = cvt8(*(const float4*)(w1 + k), *(const float4*)(w1 + k + 4));
        short8 b2 = cvt8(*(const float4*)(w2 + k), *(const float4*)(w2 + k + 4));
        short8 b3 = cvt8(*(const float4*)(w3 + k), *(const float4*)(w3 + k + 4));
        acc[0] = __builtin_amdgcn_mfma_f32_16x16x32_bf16(af, b0, acc[0], 0, 0, 0);
        acc[1] = __builtin_amdgcn_mfma_f32_16x16x32_bf16(af, b1, acc[1], 0, 0, 0);
        acc[2] = __builtin_amdgcn_mfma_f32_16x16x32_bf16(af, b2, acc[2], 0, 0, 0);
        acc[3] = __builtin_amdgcn_mfma_f32_16x16x32_bf16(af, b3, acc[3], 0, 0, 0);
    }

    // Epilogue: D[row=kq*4+i][col=m] per j-tile; write exp(2*(acc+bias))
    #pragma unroll
    for (int j = 0; j < 4; ++j) {
        const int col = col0 + j * 16 + m;
        const float bb = bias ? bias[col] : 0.f;
        #pragma unroll
        for (int i = 0; i < 4; ++i) {
            const int row = row0 + wave * 16 + kq * 4 + i;
            outp[(size_t)row * H_ + col] = __expf(2.f * (acc[j][i] + bb));
        }
    }
}

// ---------------------------------------------------------------------------
// Kernel 2: scoring. Grid 512 = b(8) x ctile(8: 64c) x qgroup(8: 8q).
// Lane owns one c; wave owns 2 q (q-side LDS reads are wave-uniform
// broadcasts). logit = b_o + Sum(W_o) - 2*sum_h W_o[h]/(Ec[c,h]*Eq[q,h]+1).
// Writes e = mask * exp(logit).
// ---------------------------------------------------------------------------
__global__ __launch_bounds__(256) void score_kernel(
    const float* __restrict__ Ec,    // B*CTX*H
    const float* __restrict__ Eqm,   // B*NQ*H
    const float* __restrict__ W_o,   // H
    const float* __restrict__ b_o_p, // scalar
    const float* __restrict__ mask,  // B*CTX
    float* __restrict__ eout)        // B*NQ*CTX
{
    __shared__ float eqs[8][H_];
    __shared__ float wos[H_];
    __shared__ float ecs[64][68];    // 64c x 64h chunk, stride-68 pad
    __shared__ float redS[4];

    const int blk = blockIdx.x;
    const int b  = blk & 7;          // XCD swizzle
    const int ctile = (blk >> 3) & 7;
    const int qg = blk >> 6;
    const int t  = threadIdx.x;

    const float* eqb = Eqm + (size_t)(b * NQ_ + qg * 8) * H_;
    #pragma unroll
    for (int i = 0; i < 8; ++i) ((float*)eqs)[t + 256 * i] = eqb[t + 256 * i];
    const float wo_own = W_o[t];
    wos[t] = wo_own;
    float S = wo_own;
    #pragma unroll
    for (int k = 1; k < 64; k <<= 1) S += __shfl_xor(S, k);
    if ((t & 63) == 0) redS[t >> 6] = S;
    __syncthreads();
    const float base = *b_o_p + redS[0] + redS[1] + redS[2] + redS[3];

    const int cl = t & 63;           // lane's c within tile
    const int qi = t >> 6;           // wave's q-pair
    const int c0 = ctile * 64;
    const float* ec_tile = Ec + (size_t)(b * CTX_ + c0) * H_;
    const int sr = t >> 2, sseg = (t & 3) * 16;       // staging map
    const float* ssrc = ec_tile + (size_t)sr * H_ + sseg;
    const float* eqa = eqs[qi * 2];
    const float* eqc = eqs[qi * 2 + 1];

    float s0 = 0.f, s1 = 0.f;
    for (int hb = 0; hb < 4; ++hb) {
        float4 v0 = *(const float4*)(ssrc + hb * 64);
        float4 v1 = *(const float4*)(ssrc + hb * 64 + 4);
        float4 v2 = *(const float4*)(ssrc + hb * 64 + 8);
        float4 v3 = *(const float4*)(ssrc + hb * 64 + 12);
        __syncthreads();             // prior chunk's compute done
        float* dst = &ecs[sr][sseg];
        *(float4*)(dst)     = v0; *(float4*)(dst + 4)  = v1;
        *(float4*)(dst + 8) = v2; *(float4*)(dst + 12) = v3;
        __syncthreads();
        const int ho = hb * 64;
        #pragma unroll
        for (int h4 = 0; h4 < 16; ++h4) {
            float4 ea = *(const float4*)&ecs[cl][h4 * 4];
            float4 qa = *(const float4*)(eqa + ho + h4 * 4);   // broadcast
            float4 qc = *(const float4*)(eqc + ho + h4 * 4);   // broadcast
            float4 w4 = *(const float4*)(wos + ho + h4 * 4);   // broadcast
            s0 += w4.x * __builtin_amdgcn_rcpf(ea.x * qa.x + 1.f);
            s0 += w4.y * __builtin_amdgcn_rcpf(ea.y * qa.y + 1.f);
            s0 += w4.z * __builtin_amdgcn_rcpf(ea.z * qa.z + 1.f);
            s0 += w4.w * __builtin_amdgcn_rcpf(ea.w * qa.w + 1.f);
            s1 += w4.x * __builtin_amdgcn_rcpf(ea.x * qc.x + 1.f);
            s1 += w4.y * __builtin_amdgcn_rcpf(ea.y * qc.y + 1.f);
            s1 += w4.z * __builtin_amdgcn_rcpf(ea.z * qc.z + 1.f);
            s1 += w4.w * __builtin_amdgcn_rcpf(ea.w * qc.w + 1.f);
        }
    }

    const int c = c0 + cl;
    const float mk = mask[b * CTX_ + c];
    const int qa_ = b * NQ_ + qg * 8 + qi * 2;
    eout[(size_t)qa_ * CTX_ + c]       = mk * __expf(base - 2.f * s0);
    eout[(size_t)(qa_ + 1) * CTX_ + c] = mk * __expf(base - 2.f * s1);
}

// ---------------------------------------------------------------------------
// Kernel 3: softmax (reference-exact: denom = sum + EPS) + weighted context
// sum. Grid 512 = b(8) x qgroup(8: 8q) x dq(8: 64d). Thread owns one d for
// ALL 8 q (weights = wave-uniform b128 broadcasts), c split 4-ways.
// ---------------------------------------------------------------------------
__global__ __launch_bounds__(256) void out_kernel(
    const float* __restrict__ eout,    // B*NQ*CTX (mask*exp(logit))
    const float* __restrict__ context, // B*CTX*DC
    float* __restrict__ out,           // B*NQ*DC
    float* __restrict__ wout)          // B*NQ*CTX
{
    __shared__ float ws[CTX_][8];      // q-major weights: 16 KB
    __shared__ float pc[3][64][8];     // partial sums: 6 KB

    const int blk = blockIdx.x;
    const int b  = blk & 7;
    const int qg = (blk >> 3) & 7;
    const int dq = blk >> 6;           // 0..7: d in [dq*64, +64)
    const int t  = threadIdx.x;

    // Phase 1: softmax for the 8 q of this qgroup
    {
        const int qi = t >> 5;         // 0..7
        const int cl = t & 31;
        const int q = b * NQ_ + qg * 8 + qi;
        const float* erow = eout + (size_t)q * CTX_;
        float ev[16];
        float part = 0.f;
        #pragma unroll
        for (int k = 0; k < 16; ++k) { ev[k] = erow[cl + 32 * k]; part += ev[k]; }
        part += __shfl_xor(part, 1);  part += __shfl_xor(part, 2);
        part += __shfl_xor(part, 4);  part += __shfl_xor(part, 8);
        part += __shfl_xor(part, 16);
        const float inv = 1.f / (part + EPS_);
        #pragma unroll
        for (int k = 0; k < 16; ++k) {
            const float w = ev[k] * inv;
            ws[cl + 32 * k][qi] = w;
            if (dq == 0) wout[(size_t)q * CTX_ + cl + 32 * k] = w;
        }
    }
    __syncthreads();

    // Phase 2: weighted sum; cq4 = c-quarter, dt = d-lane
    const int cq4 = t >> 6;            // 0..3
    const int dt  = t & 63;
    const int d   = dq * 64 + dt;
    const float* cb = context + ((size_t)(b * CTX_) + cq4 * 128) * DC_ + d;

    float a0=0,a1=0,a2=0,a3=0,a4=0,a5=0,a6=0,a7=0;
    #pragma unroll 4
    for (int c = 0; c < 128; ++c) {
        const float4 wA = *(const float4*)&ws[cq4 * 128 + c][0];  // broadcast
        const float4 wB = *(const float4*)&ws[cq4 * 128 + c][4];  // broadcast
        const float v = cb[(size_t)c * DC_];
        a0 += wA.x * v; a1 += wA.y * v; a2 += wA.z * v; a3 += wA.w * v;
        a4 += wB.x * v; a5 += wB.y * v; a6 += wB.z * v; a7 += wB.w * v;
    }
    if (cq4) {
        float* p = pc[cq4 - 1][dt];
        p[0]=a0; p[1]=a1; p[2]=a2; p[3]=a3; p[4]=a4; p[5]=a5; p[6]=a6; p[7]=a7;
    }
    __syncthreads();
    if (cq4 == 0) {
        float r[8] = {a0,a1,a2,a3,a4,a5,a6,a7};
        #pragma unroll
        for (int j = 0; j < 8; ++j)
            r[j] += pc[0][dt][j] + pc[1][dt][j] + pc[2][dt][j];
        const int qbase = b * NQ_ + qg * 8;
        #pragma unroll
        for (int j = 0; j < 8; ++j)
            out[(size_t)(qbase + j) * DC_ + d] = r[j];
    }
}

extern "C" void kernel_launch(void* const* d_in, const int* in_sizes, int n_in,
                              void* d_out, int out_size, void* d_ws, size_t ws_size,
                              hipStream_t stream) {
    const float* query   = (const float*)d_in[0];  // B,NQ,DQ
    const float* context = (const float*)d_in[1];  // B,CTX,DC
    const float* mask    = (const float*)d_in[2];  // B,CTX
    const float* W_c     = (const float*)d_in[3];  // H,DC
    const float* b_c     = (const float*)d_in[4];  // H
    const float* W_q     = (const float*)d_in[5];  // H,DQ
    const float* W_o     = (const float*)d_in[6];  // H
    const float* b_o     = (const float*)d_in[7];  // scalar

    float* out  = (float*)d_out;                   // B,NQ,DC
    float* wout = out + (size_t)B_ * NQ_ * DC_;    // B,NQ,CTX

    float* Ec   = (float*)d_ws;                        // 4 MB: exp(2*res_c)
    float* Eq   = Ec + (size_t)B_ * CTX_ * H_;         // 512 KB: exp(2*res_q)
    float* eout = Eq + (size_t)B_ * NQ_ * H_;          // 1 MB: mask*exp(logit)

    gemm_exp<<<dim3(72, 4), 256, 0, stream>>>(
        context, query, W_c, b_c, W_q, Ec, Eq);
    score_kernel<<<512, 256, 0, stream>>>(
        Ec, Eq, W_o, b_o, mask, eout);
    out_kernel<<<512, 256, 0, stream>>>(
        eout, context, out, wout);
}

// Round 6
// 108.648 us; speedup vs baseline: 1.4053x; 1.2659x over previous
//
#include <hip/hip_runtime.h>
#include <hip/hip_bf16.h>

// Problem constants (match reference)
#define B_   8
#define NQ_  64     // N_CANDS
#define CTX_ 512    // CTX_LEN
#define DC_  512    // CONTEXT_SIZE
#define DQ_  512    // QUERY_SIZE
#define H_   256    // HIDDEN
#define EPS_ 1e-5f

using short8  = __attribute__((ext_vector_type(8))) short;  // 8 bf16 (4 VGPRs)
using floatx4 = __attribute__((ext_vector_type(4))) float;  // MFMA acc

// 2 fp32 -> packed bf16x2 via v_cvt_pk_bf16_f32 (single instruction on gfx950)
__device__ __forceinline__ unsigned pk2(float x, float y) {
    union { __hip_bfloat162 h; unsigned u; } c;
    c.h = __float22bfloat162_rn(make_float2(x, y));
    return c.u;
}
// 8 fp32 (two float4) -> 16B packed bf16
__device__ __forceinline__ uint4 cvt8u(float4 a, float4 b) {
    uint4 r;
    r.x = pk2(a.x, a.y); r.y = pk2(a.z, a.w);
    r.z = pk2(b.x, b.y); r.w = pk2(b.z, b.w);
    return r;
}

// ---------------------------------------------------------------------------
// Kernel 1: both input GEMMs via bf16 MFMA, LDS-staged with register prefetch.
// Epilogue: Ec = exp(2*(acc+bias)), Eq = exp(2*acc)   (factored-exp form:
// tanh(x) = 1 - 2/(e^{2x}+1), e^{2(rc+rq)} = Ec*Eq).
// Tile 32Mx64N, BK=64; grid 144x4 = 576 blocks (2.25/CU) for latency hiding.
// 256 thr = 4 waves: wave = (mh = w>>1) 16-row half x (nh = w&1) 32-col half.
// Staging: thread owns 3 contiguous 8-float chunks -> cvt_pk -> ds_write_b128.
// LDS row stride 72 shorts: fragment b128 reads spread over all 32 banks.
// ---------------------------------------------------------------------------
__global__ __launch_bounds__(256) void gemm_exp(
    const float* __restrict__ ctx, const float* __restrict__ query,
    const float* __restrict__ W_c, const float* __restrict__ b_c,
    const float* __restrict__ W_q,
    float* __restrict__ Ec, float* __restrict__ Eq)
{
    __shared__ unsigned short As[32][72];   // 32 rows x 64 bf16 (+8 pad)
    __shared__ unsigned short Bs[64][72];   // 64 rows x 64 bf16 (+8 pad)

    const int rt = blockIdx.x;     // 0..143 (128 ctx + 16 query row-tiles)
    const int ct = blockIdx.y;     // 0..3

    const float* A; const float* W; const float* bias; float* outp; int row0;
    if (rt < 128) { A = ctx;   W = W_c; bias = b_c;     outp = Ec; row0 = rt * 32; }
    else          { A = query; W = W_q; bias = nullptr; outp = Eq; row0 = (rt - 128) * 32; }

    const int col0 = ct * 64;
    const int t    = threadIdx.x;
    const int wave = t >> 6;
    const int lane = t & 63;
    const int m  = lane & 15;
    const int kq = lane >> 4;
    const int mh = wave >> 1;      // M-half: rows mh*16..+16
    const int nh = wave & 1;       // N-half: cols nh*32..+32

    // staging ownership: chunk = 8 fp32 contiguous; r = t>>3, s = t&7
    const int sr = t >> 3, ss = t & 7;
    const float* gA  = A + (size_t)(row0 + sr) * 512 + ss * 8;
    const float* gB0 = W + (size_t)(col0 + sr) * 512 + ss * 8;
    const float* gB1 = W + (size_t)(col0 + 32 + sr) * 512 + ss * 8;
    unsigned short* lA  = &As[sr][ss * 8];
    unsigned short* lB0 = &Bs[sr][ss * 8];
    unsigned short* lB1 = &Bs[32 + sr][ss * 8];

    floatx4 acc[2] = {};
    float4 pA0, pA1, pB00, pB01, pB10, pB11;

    // prologue loads (k0 = 0)
    pA0  = *(const float4*)(gA);       pA1  = *(const float4*)(gA + 4);
    pB00 = *(const float4*)(gB0);      pB01 = *(const float4*)(gB0 + 4);
    pB10 = *(const float4*)(gB1);      pB11 = *(const float4*)(gB1 + 4);

    for (int s = 0; s < 8; ++s) {
        __syncthreads();               // readers of previous step done
        *(uint4*)lA  = cvt8u(pA0, pA1);
        *(uint4*)lB0 = cvt8u(pB00, pB01);
        *(uint4*)lB1 = cvt8u(pB10, pB11);
        __syncthreads();

        if (s < 7) {                   // prefetch next step (overlaps compute)
            const int k = (s + 1) * 64;
            pA0  = *(const float4*)(gA + k);   pA1  = *(const float4*)(gA + k + 4);
            pB00 = *(const float4*)(gB0 + k);  pB01 = *(const float4*)(gB0 + k + 4);
            pB10 = *(const float4*)(gB1 + k);  pB11 = *(const float4*)(gB1 + k + 4);
        }

        #pragma unroll
        for (int kc = 0; kc < 2; ++kc) {
            short8 af = *(const short8*)&As[mh * 16 + m][kc * 32 + kq * 8];
            short8 b0 = *(const short8*)&Bs[nh * 32 +      m][kc * 32 + kq * 8];
            short8 b1 = *(const short8*)&Bs[nh * 32 + 16 + m][kc * 32 + kq * 8];
            acc[0] = __builtin_amdgcn_mfma_f32_16x16x32_bf16(af, b0, acc[0], 0, 0, 0);
            acc[1] = __builtin_amdgcn_mfma_f32_16x16x32_bf16(af, b1, acc[1], 0, 0, 0);
        }
    }

    // Epilogue: D[row=kq*4+i][col=m] per j-tile; write exp(2*(acc+bias))
    #pragma unroll
    for (int j = 0; j < 2; ++j) {
        const int col = col0 + nh * 32 + j * 16 + m;
        const float bb = bias ? bias[col] : 0.f;
        #pragma unroll
        for (int i = 0; i < 4; ++i) {
            const int row = row0 + mh * 16 + kq * 4 + i;
            outp[(size_t)row * H_ + col] = __expf(2.f * (acc[j][i] + bb));
        }
    }
}

// ---------------------------------------------------------------------------
// Kernel 2: scoring. Grid 512 = b(8) x ctile(8: 64c) x qgroup(8: 8q).
// Lane owns one c; wave owns 2 q (q-side LDS reads are wave-uniform
// broadcasts). logit = b_o + Sum(W_o) - 2*sum_h W_o[h]/(Ec[c,h]*Eq[q,h]+1).
// Writes e = mask * exp(logit).
// ---------------------------------------------------------------------------
__global__ __launch_bounds__(256) void score_kernel(
    const float* __restrict__ Ec,    // B*CTX*H
    const float* __restrict__ Eqm,   // B*NQ*H
    const float* __restrict__ W_o,   // H
    const float* __restrict__ b_o_p, // scalar
    const float* __restrict__ mask,  // B*CTX
    float* __restrict__ eout)        // B*NQ*CTX
{
    __shared__ float eqs[8][H_];
    __shared__ float wos[H_];
    __shared__ float ecs[64][68];    // 64c x 64h chunk, stride-68 pad
    __shared__ float redS[4];

    const int blk = blockIdx.x;
    const int b  = blk & 7;          // XCD swizzle
    const int ctile = (blk >> 3) & 7;
    const int qg = blk >> 6;
    const int t  = threadIdx.x;

    const float* eqb = Eqm + (size_t)(b * NQ_ + qg * 8) * H_;
    #pragma unroll
    for (int i = 0; i < 8; ++i) ((float*)eqs)[t + 256 * i] = eqb[t + 256 * i];
    const float wo_own = W_o[t];
    wos[t] = wo_own;
    float S = wo_own;
    #pragma unroll
    for (int k = 1; k < 64; k <<= 1) S += __shfl_xor(S, k);
    if ((t & 63) == 0) redS[t >> 6] = S;
    __syncthreads();
    const float base = *b_o_p + redS[0] + redS[1] + redS[2] + redS[3];

    const int cl = t & 63;           // lane's c within tile
    const int qi = t >> 6;           // wave's q-pair
    const int c0 = ctile * 64;
    const float* ec_tile = Ec + (size_t)(b * CTX_ + c0) * H_;
    const int sr = t >> 2, sseg = (t & 3) * 16;       // staging map
    const float* ssrc = ec_tile + (size_t)sr * H_ + sseg;
    const float* eqa = eqs[qi * 2];
    const float* eqc = eqs[qi * 2 + 1];

    float s0 = 0.f, s1 = 0.f;
    for (int hb = 0; hb < 4; ++hb) {
        float4 v0 = *(const float4*)(ssrc + hb * 64);
        float4 v1 = *(const float4*)(ssrc + hb * 64 + 4);
        float4 v2 = *(const float4*)(ssrc + hb * 64 + 8);
        float4 v3 = *(const float4*)(ssrc + hb * 64 + 12);
        __syncthreads();             // prior chunk's compute done
        float* dst = &ecs[sr][sseg];
        *(float4*)(dst)     = v0; *(float4*)(dst + 4)  = v1;
        *(float4*)(dst + 8) = v2; *(float4*)(dst + 12) = v3;
        __syncthreads();
        const int ho = hb * 64;
        #pragma unroll
        for (int h4 = 0; h4 < 16; ++h4) {
            float4 ea = *(const float4*)&ecs[cl][h4 * 4];
            float4 qa = *(const float4*)(eqa + ho + h4 * 4);   // broadcast
            float4 qc = *(const float4*)(eqc + ho + h4 * 4);   // broadcast
            float4 w4 = *(const float4*)(wos + ho + h4 * 4);   // broadcast
            s0 += w4.x * __builtin_amdgcn_rcpf(ea.x * qa.x + 1.f);
            s0 += w4.y * __builtin_amdgcn_rcpf(ea.y * qa.y + 1.f);
            s0 += w4.z * __builtin_amdgcn_rcpf(ea.z * qa.z + 1.f);
            s0 += w4.w * __builtin_amdgcn_rcpf(ea.w * qa.w + 1.f);
            s1 += w4.x * __builtin_amdgcn_rcpf(ea.x * qc.x + 1.f);
            s1 += w4.y * __builtin_amdgcn_rcpf(ea.y * qc.y + 1.f);
            s1 += w4.z * __builtin_amdgcn_rcpf(ea.z * qc.z + 1.f);
            s1 += w4.w * __builtin_amdgcn_rcpf(ea.w * qc.w + 1.f);
        }
    }

    const int c = c0 + cl;
    const float mk = mask[b * CTX_ + c];
    const int qa_ = b * NQ_ + qg * 8 + qi * 2;
    eout[(size_t)qa_ * CTX_ + c]       = mk * __expf(base - 2.f * s0);
    eout[(size_t)(qa_ + 1) * CTX_ + c] = mk * __expf(base - 2.f * s1);
}

// ---------------------------------------------------------------------------
// Kernel 3: softmax (reference-exact: denom = sum + EPS) + weighted context
// sum. Grid 512 = b(8) x qgroup(8: 8q) x dq(8: 64d). Thread owns one d for
// ALL 8 q (weights = wave-uniform b128 broadcasts), c split 4-ways.
// ---------------------------------------------------------------------------
__global__ __launch_bounds__(256) void out_kernel(
    const float* __restrict__ eout,    // B*NQ*CTX (mask*exp(logit))
    const float* __restrict__ context, // B*CTX*DC
    float* __restrict__ out,           // B*NQ*DC
    float* __restrict__ wout)          // B*NQ*CTX
{
    __shared__ float ws[CTX_][8];      // q-major weights: 16 KB
    __shared__ float pc[3][64][8];     // partial sums: 6 KB

    const int blk = blockIdx.x;
    const int b  = blk & 7;
    const int qg = (blk >> 3) & 7;
    const int dq = blk >> 6;           // 0..7: d in [dq*64, +64)
    const int t  = threadIdx.x;

    // Phase 1: softmax for the 8 q of this qgroup
    {
        const int qi = t >> 5;         // 0..7
        const int cl = t & 31;
        const int q = b * NQ_ + qg * 8 + qi;
        const float* erow = eout + (size_t)q * CTX_;
        float ev[16];
        float part = 0.f;
        #pragma unroll
        for (int k = 0; k < 16; ++k) { ev[k] = erow[cl + 32 * k]; part += ev[k]; }
        part += __shfl_xor(part, 1);  part += __shfl_xor(part, 2);
        part += __shfl_xor(part, 4);  part += __shfl_xor(part, 8);
        part += __shfl_xor(part, 16);
        const float inv = 1.f / (part + EPS_);
        #pragma unroll
        for (int k = 0; k < 16; ++k) {
            const float w = ev[k] * inv;
            ws[cl + 32 * k][qi] = w;
            if (dq == 0) wout[(size_t)q * CTX_ + cl + 32 * k] = w;
        }
    }
    __syncthreads();

    // Phase 2: weighted sum; cq4 = c-quarter, dt = d-lane
    const int cq4 = t >> 6;            // 0..3
    const int dt  = t & 63;
    const int d   = dq * 64 + dt;
    const float* cb = context + ((size_t)(b * CTX_) + cq4 * 128) * DC_ + d;

    float a0=0,a1=0,a2=0,a3=0,a4=0,a5=0,a6=0,a7=0;
    #pragma unroll 4
    for (int c = 0; c < 128; ++c) {
        const float4 wA = *(const float4*)&ws[cq4 * 128 + c][0];  // broadcast
        const float4 wB = *(const float4*)&ws[cq4 * 128 + c][4];  // broadcast
        const float v = cb[(size_t)c * DC_];
        a0 += wA.x * v; a1 += wA.y * v; a2 += wA.z * v; a3 += wA.w * v;
        a4 += wB.x * v; a5 += wB.y * v; a6 += wB.z * v; a7 += wB.w * v;
    }
    if (cq4) {
        float* p = pc[cq4 - 1][dt];
        p[0]=a0; p[1]=a1; p[2]=a2; p[3]=a3; p[4]=a4; p[5]=a5; p[6]=a6; p[7]=a7;
    }
    __syncthreads();
    if (cq4 == 0) {
        float r[8] = {a0,a1,a2,a3,a4,a5,a6,a7};
        #pragma unroll
        for (int j = 0; j < 8; ++j)
            r[j] += pc[0][dt][j] + pc[1][dt][j] + pc[2][dt][j];
        const int qbase = b * NQ_ + qg * 8;
        #pragma unroll
        for (int j = 0; j < 8; ++j)
            out[(size_t)(qbase + j) * DC_ + d] = r[j];
    }
}

extern "C" void kernel_launch(void* const* d_in, const int* in_sizes, int n_in,
                              void* d_out, int out_size, void* d_ws, size_t ws_size,
                              hipStream_t stream) {
    const float* query   = (const float*)d_in[0];  // B,NQ,DQ
    const float* context = (const float*)d_in[1];  // B,CTX,DC
    const float* mask    = (const float*)d_in[2];  // B,CTX
    const float* W_c     = (const float*)d_in[3];  // H,DC
    const float* b_c     = (const float*)d_in[4];  // H
    const float* W_q     = (const float*)d_in[5];  // H,DQ
    const float* W_o     = (const float*)d_in[6];  // H
    const float* b_o     = (const float*)d_in[7];  // scalar

    float* out  = (float*)d_out;                   // B,NQ,DC
    float* wout = out + (size_t)B_ * NQ_ * DC_;    // B,NQ,CTX

    float* Ec   = (float*)d_ws;                        // 4 MB: exp(2*res_c)
    float* Eq   = Ec + (size_t)B_ * CTX_ * H_;         // 512 KB: exp(2*res_q)
    float* eout = Eq + (size_t)B_ * NQ_ * H_;          // 1 MB: mask*exp(logit)

    gemm_exp<<<dim3(144, 4), 256, 0, stream>>>(
        context, query, W_c, b_c, W_q, Ec, Eq);
    score_kernel<<<512, 256, 0, stream>>>(
        Ec, Eq, W_o, b_o, mask, eout);
    out_kernel<<<512, 256, 0, stream>>>(
        eout, context, out, wout);
}